// Round 4
// baseline (603.478 us; speedup 1.0000x reference)
//
#include <hip/hip_runtime.h>
#include <hip/hip_bf16.h>
#include <cstdint>
#include <cstddef>

#define NNODES 50000
#define NEDGES 800000
#define DF 64
#define KM 192      // msg MLP input dim (3*D)
#define KU 128      // upd MLP input dim (2*D)

typedef __bf16 bf16_t;
typedef __bf16 bf16x8 __attribute__((ext_vector_type(8)));
typedef __bf16 bf16x4 __attribute__((ext_vector_type(4)));
typedef float  f32x4  __attribute__((ext_vector_type(4)));

// LDS tile: 64 rows x 256 bf16 elems (512 B row) = 32768 B exactly -> 5 blocks/CU.
// Row stride 512 B alone = 16-way bank conflict (bank period 128 B), so XOR-swizzle
// the elem index with (row&7)<<3 (byte bits 4-6): preserves 16/8/4/2 B alignment,
// spreads the 16 same-column lanes across 8 distinct 16B slots -> 2-way (free).
__device__ __forceinline__ int swz(int row, int e) {
    return row * 256 + (e ^ ((row & 7) << 3));
}

// ---------------------------------------------------------------------------
// Weight packing: W[K][N] fp32 row-major  ->  bf16 MFMA B-fragments.
// Fragment (kblk, ct): lane l, elem j holds W[kblk*32 + (l>>4)*8 + j][ct*16 + (l&15)]
// Flat: ((kblk*(N/16) + ct)*64 + l)*8 + j.
// Segments: Wm1 @0 (49152), Wm2 @49152 (16384), Wu1 @65536 (32768), Wu2 @98304 (16384).
// ---------------------------------------------------------------------------
__global__ void prep_kernel(const float* __restrict__ Wm1, const float* __restrict__ Wm2,
                            const float* __restrict__ Wu1, const float* __restrict__ Wu2,
                            bf16_t* __restrict__ wp)
{
    int idx = blockIdx.x * 256 + threadIdx.x;
    const float* src; int N; int off; int local;
    if (idx < 49152)       { src = Wm1; N = 256; off = 0;     local = idx; }
    else if (idx < 65536)  { src = Wm2; N = 64;  off = 49152; local = idx - 49152; }
    else if (idx < 98304)  { src = Wu1; N = 256; off = 65536; local = idx - 65536; }
    else if (idx < 114688) { src = Wu2; N = 64;  off = 98304; local = idx - 98304; }
    else return;
    int j    = local & 7;
    int l    = (local >> 3) & 63;
    int frag = local >> 9;
    int nct  = N >> 4;
    int kblk = frag / nct;
    int ct   = frag - kblk * nct;
    int k = kblk * 32 + (l >> 4) * 8 + j;
    int n = ct * 16 + (l & 15);
    wp[off + local] = (bf16_t)src[(size_t)k * N + n];
}

// ---------------------------------------------------------------------------
// Message kernel: 64 edges/block, 4 waves, N-split across waves.
//   layer1: wave w computes all 64 edges x cols [w*64, w*64+64)
//   layer2: wave w computes all 64 edges x cols [w*16, w*16+16)
// snd/rcv read straight from global (64 consecutive ints, L1-broadcast).
// 3 barriers. LDS exactly 32 KiB -> 5 blocks/CU.
// ---------------------------------------------------------------------------
__global__ __launch_bounds__(256, 5)
void msg_kernel(const float* __restrict__ h, const float* __restrict__ efeat,
                const int* __restrict__ snd, const int* __restrict__ rcv,
                const bf16_t* __restrict__ Wp1, const float* __restrict__ b1,
                const bf16_t* __restrict__ Wp2, const float* __restrict__ b2,
                float* __restrict__ agg)
{
    __shared__ bf16_t s_buf[64 * 256];   // 32768 B exactly — nothing else in LDS

    const int t  = threadIdx.x;
    const int e0 = blockIdx.x * 64;

    // gather m_in = [e | h_s | h_r] : 64 rows x 192 cols (float4 granularity)
    #pragma unroll
    for (int it = 0; it < 12; ++it) {
        int i   = t + it * 256;        // < 3072 = 64*48
        int ee  = i / 48;
        int c4  = i - ee * 48;
        int col = c4 * 4;
        const float* srcp;
        if (col < DF)          srcp = efeat + (size_t)(e0 + ee) * DF + col;
        else if (col < 2 * DF) srcp = h + (size_t)snd[e0 + ee] * DF + (col - DF);
        else                   srcp = h + (size_t)rcv[e0 + ee] * DF + (col - 2 * DF);
        float4 v = *reinterpret_cast<const float4*>(srcp);
        bf16x4 bv;
        bv[0] = (bf16_t)v.x; bv[1] = (bf16_t)v.y; bv[2] = (bf16_t)v.z; bv[3] = (bf16_t)v.w;
        *reinterpret_cast<bf16x4*>(&s_buf[swz(ee, col)]) = bv;
    }
    __syncthreads();

    const int w = t >> 6;
    const int l = t & 63;
    const int q = l >> 4;
    const int r = l & 15;

    // ---- layer 1: M=64 (4 row-frags), N=64 per wave (4 ct) ----
    f32x4 acc[4][4];   // [g][am]
    #pragma unroll
    for (int g = 0; g < 4; ++g)
        #pragma unroll
        for (int am = 0; am < 4; ++am) acc[g][am] = (f32x4){0.f, 0.f, 0.f, 0.f};

    #pragma unroll
    for (int kb = 0; kb < 6; ++kb) {
        bf16x8 a[4];
        #pragma unroll
        for (int am = 0; am < 4; ++am)
            a[am] = *reinterpret_cast<const bf16x8*>(&s_buf[swz(am * 16 + r, kb * 32 + q * 8)]);
        #pragma unroll
        for (int g = 0; g < 4; ++g) {
            int ct = w * 4 + g;
            bf16x8 b = *reinterpret_cast<const bf16x8*>(Wp1 + ((size_t)(kb * 16 + ct) * 64 + l) * 8);
            #pragma unroll
            for (int am = 0; am < 4; ++am)
                acc[g][am] = __builtin_amdgcn_mfma_f32_16x16x32_bf16(a[am], b, acc[g][am], 0, 0, 0);
        }
    }
    __syncthreads();   // everyone done reading the input tile

    // bias + relu -> c1 into s_buf (row = edge, col = hidden unit)
    #pragma unroll
    for (int g = 0; g < 4; ++g) {
        int col = (w * 4 + g) * 16 + r;
        float bias = b1[col];
        #pragma unroll
        for (int am = 0; am < 4; ++am)
            #pragma unroll
            for (int j = 0; j < 4; ++j)
                s_buf[swz(am * 16 + q * 4 + j, col)] =
                    (bf16_t)fmaxf(acc[g][am][j] + bias, 0.f);
    }
    __syncthreads();   // c1 complete

    // ---- layer 2: M=64, N=16 per wave (ct = w) ----
    f32x4 acc2[4];
    #pragma unroll
    for (int am = 0; am < 4; ++am) acc2[am] = (f32x4){0.f, 0.f, 0.f, 0.f};

    #pragma unroll
    for (int kb = 0; kb < 8; ++kb) {
        bf16x8 a[4];
        #pragma unroll
        for (int am = 0; am < 4; ++am)
            a[am] = *reinterpret_cast<const bf16x8*>(&s_buf[swz(am * 16 + r, kb * 32 + q * 8)]);
        bf16x8 b = *reinterpret_cast<const bf16x8*>(Wp2 + ((size_t)(kb * 4 + w) * 64 + l) * 8);
        #pragma unroll
        for (int am = 0; am < 4; ++am)
            acc2[am] = __builtin_amdgcn_mfma_f32_16x16x32_bf16(a[am], b, acc2[am], 0, 0, 0);
    }

    // scatter (+bias): col = w*16 + r. rcv re-read from global (L1-hot, broadcast).
    float bias2 = b2[w * 16 + r];
    #pragma unroll
    for (int am = 0; am < 4; ++am)
        #pragma unroll
        for (int j = 0; j < 4; ++j) {
            int el = am * 16 + q * 4 + j;
            int rv = rcv[e0 + el];
            atomicAdd(agg + (size_t)rv * DF + w * 16 + r, acc2[am][j] + bias2);
        }
}

// ---------------------------------------------------------------------------
// Node-update kernel: 64 nodes/block, same template, K=128, residual store.
// Alias-safe when agg==out: agg reads happen only in the gather (pre-barrier);
// stores come after the final barrier.
// ---------------------------------------------------------------------------
__global__ __launch_bounds__(256, 5)
void upd_kernel(const float* __restrict__ h, const float* __restrict__ agg,
                const bf16_t* __restrict__ Wp1, const float* __restrict__ b1,
                const bf16_t* __restrict__ Wp2, const float* __restrict__ b2,
                float* __restrict__ out)
{
    __shared__ bf16_t s_buf[64 * 256];   // 32768 B exactly

    const int t  = threadIdx.x;
    const int n0 = blockIdx.x * 64;

    // gather u_in = [h | agg] : 64 rows x 128 cols
    #pragma unroll
    for (int it = 0; it < 8; ++it) {
        int i    = t + it * 256;       // < 2048 = 64*32
        int nn   = i >> 5;
        int col  = (i & 31) * 4;
        int node = n0 + nn;
        float4 v;
        if (node < NNODES) {
            const float* srcp = (col < DF) ? (h + (size_t)node * DF + col)
                                           : (agg + (size_t)node * DF + (col - DF));
            v = *reinterpret_cast<const float4*>(srcp);
        } else {
            v.x = 0.f; v.y = 0.f; v.z = 0.f; v.w = 0.f;
        }
        bf16x4 bv;
        bv[0] = (bf16_t)v.x; bv[1] = (bf16_t)v.y; bv[2] = (bf16_t)v.z; bv[3] = (bf16_t)v.w;
        *reinterpret_cast<bf16x4*>(&s_buf[swz(nn, col)]) = bv;
    }
    __syncthreads();

    const int w = t >> 6;
    const int l = t & 63;
    const int q = l >> 4;
    const int r = l & 15;

    f32x4 acc[4][4];
    #pragma unroll
    for (int g = 0; g < 4; ++g)
        #pragma unroll
        for (int am = 0; am < 4; ++am) acc[g][am] = (f32x4){0.f, 0.f, 0.f, 0.f};

    #pragma unroll
    for (int kb = 0; kb < 4; ++kb) {
        bf16x8 a[4];
        #pragma unroll
        for (int am = 0; am < 4; ++am)
            a[am] = *reinterpret_cast<const bf16x8*>(&s_buf[swz(am * 16 + r, kb * 32 + q * 8)]);
        #pragma unroll
        for (int g = 0; g < 4; ++g) {
            int ct = w * 4 + g;
            bf16x8 b = *reinterpret_cast<const bf16x8*>(Wp1 + ((size_t)(kb * 16 + ct) * 64 + l) * 8);
            #pragma unroll
            for (int am = 0; am < 4; ++am)
                acc[g][am] = __builtin_amdgcn_mfma_f32_16x16x32_bf16(a[am], b, acc[g][am], 0, 0, 0);
        }
    }
    __syncthreads();

    #pragma unroll
    for (int g = 0; g < 4; ++g) {
        int col = (w * 4 + g) * 16 + r;
        float bias = b1[col];
        #pragma unroll
        for (int am = 0; am < 4; ++am)
            #pragma unroll
            for (int j = 0; j < 4; ++j)
                s_buf[swz(am * 16 + q * 4 + j, col)] =
                    (bf16_t)fmaxf(acc[g][am][j] + bias, 0.f);
    }
    __syncthreads();

    f32x4 acc2[4];
    #pragma unroll
    for (int am = 0; am < 4; ++am) acc2[am] = (f32x4){0.f, 0.f, 0.f, 0.f};

    #pragma unroll
    for (int kb = 0; kb < 8; ++kb) {
        bf16x8 a[4];
        #pragma unroll
        for (int am = 0; am < 4; ++am)
            a[am] = *reinterpret_cast<const bf16x8*>(&s_buf[swz(am * 16 + r, kb * 32 + q * 8)]);
        bf16x8 b = *reinterpret_cast<const bf16x8*>(Wp2 + ((size_t)(kb * 4 + w) * 64 + l) * 8);
        #pragma unroll
        for (int am = 0; am < 4; ++am)
            acc2[am] = __builtin_amdgcn_mfma_f32_16x16x32_bf16(a[am], b, acc2[am], 0, 0, 0);
    }

    // residual store: out = h + dh  (col = w*16 + r)
    float bias2 = b2[w * 16 + r];
    #pragma unroll
    for (int am = 0; am < 4; ++am)
        #pragma unroll
        for (int j = 0; j < 4; ++j) {
            int node = n0 + am * 16 + q * 4 + j;
            if (node < NNODES) {
                int col = w * 16 + r;
                out[(size_t)node * DF + col] =
                    h[(size_t)node * DF + col] + acc2[am][j] + bias2;
            }
        }
}

extern "C" void kernel_launch(void* const* d_in, const int* in_sizes, int n_in,
                              void* d_out, int out_size, void* d_ws, size_t ws_size,
                              hipStream_t stream)
{
    const float* h    = (const float*)d_in[0];
    const float* e    = (const float*)d_in[1];
    const int*   snd  = (const int*)d_in[2];
    const int*   rcv  = (const int*)d_in[3];
    const float* W_m1 = (const float*)d_in[4];
    const float* b_m1 = (const float*)d_in[5];
    const float* W_m2 = (const float*)d_in[6];
    const float* b_m2 = (const float*)d_in[7];
    const float* W_u1 = (const float*)d_in[8];
    const float* b_u1 = (const float*)d_in[9];
    const float* W_u2 = (const float*)d_in[10];
    const float* b_u2 = (const float*)d_in[11];
    float* out = (float*)d_out;

    const size_t agg_bytes = (size_t)NNODES * DF * sizeof(float);   // 12.8 MB
    const size_t wp_bytes  = 114688 * sizeof(bf16_t);               // 229 KB

    float*  agg;
    bf16_t* wp;
    if (ws_size >= agg_bytes + wp_bytes) {
        agg = (float*)d_ws;
        wp  = (bf16_t*)((char*)d_ws + agg_bytes);
    } else {
        agg = out;               // alias-safe per upd_kernel structure
        wp  = (bf16_t*)d_ws;
    }

    bf16_t* Wp_m1 = wp;
    bf16_t* Wp_m2 = wp + 49152;
    bf16_t* Wp_u1 = wp + 65536;
    bf16_t* Wp_u2 = wp + 98304;

    prep_kernel<<<448, 256, 0, stream>>>(W_m1, W_m2, W_u1, W_u2, wp);
    hipMemsetAsync(agg, 0, agg_bytes, stream);

    msg_kernel<<<NEDGES / 64, 256, 0, stream>>>(h, e, snd, rcv,
                                                Wp_m1, b_m1, Wp_m2, b_m2, agg);
    upd_kernel<<<(NNODES + 63) / 64, 256, 0, stream>>>(h, agg,
                                                       Wp_u1, b_u1, Wp_u2, b_u2, out);
}

// Round 5
// 420.134 us; speedup vs baseline: 1.4364x; 1.4364x over previous
//
#include <hip/hip_runtime.h>
#include <hip/hip_bf16.h>
#include <cstdint>
#include <cstddef>

#define NNODES 50000
#define NEDGES 800000
#define DF 64
#define KM 192      // msg MLP input dim (3*D)
#define KU 128      // upd MLP input dim (2*D)

typedef __bf16 bf16_t;
typedef __bf16 bf16x8 __attribute__((ext_vector_type(8)));
typedef __bf16 bf16x4 __attribute__((ext_vector_type(4)));
typedef float  f32x4  __attribute__((ext_vector_type(4)));

// LDS tile: 64 rows x 256 bf16 (512 B row) = 32768 B exactly -> 5 blocks/CU by LDS.
// Row stride 512 B alone = 16-way bank conflict, so XOR-swizzle elem index with
// (row&7)<<3 (byte bits 4-6): preserves 16B alignment, spreads same-column lanes
// across 8 slots -> ~2-way (free).
__device__ __forceinline__ int swz(int row, int e) {
    return row * 256 + (e ^ ((row & 7) << 3));
}

// ---------------------------------------------------------------------------
// Weight packing: W[K][N] fp32 row-major -> bf16 MFMA B-fragments.
// Fragment (kblk, ct): lane l, elem j holds W[kblk*32 + (l>>4)*8 + j][ct*16 + (l&15)]
// Flat: ((kblk*(N/16) + ct)*64 + l)*8 + j.
// Segments: Wm1 @0 (49152), Wm2 @49152 (16384), Wu1 @65536 (32768), Wu2 @98304 (16384).
// ---------------------------------------------------------------------------
__global__ void prep_kernel(const float* __restrict__ Wm1, const float* __restrict__ Wm2,
                            const float* __restrict__ Wu1, const float* __restrict__ Wu2,
                            bf16_t* __restrict__ wp)
{
    int idx = blockIdx.x * 256 + threadIdx.x;
    const float* src; int N; int off; int local;
    if (idx < 49152)       { src = Wm1; N = 256; off = 0;     local = idx; }
    else if (idx < 65536)  { src = Wm2; N = 64;  off = 49152; local = idx - 49152; }
    else if (idx < 98304)  { src = Wu1; N = 256; off = 65536; local = idx - 65536; }
    else if (idx < 114688) { src = Wu2; N = 64;  off = 98304; local = idx - 98304; }
    else return;
    int j    = local & 7;
    int l    = (local >> 3) & 63;
    int frag = local >> 9;
    int nct  = N >> 4;
    int kblk = frag / nct;
    int ct   = frag - kblk * nct;
    int k = kblk * 32 + (l >> 4) * 8 + j;
    int n = ct * 16 + (l & 15);
    wp[off + local] = (bf16_t)src[(size_t)k * N + n];
}

// ---------------------------------------------------------------------------
// Message kernel: 64 edges/block, 4 waves, N-split across waves.
//   layer1: wave w computes all 64 edges x cols [w*64, w*64+64)
//   layer2: wave w computes all 64 edges x cols [w*16, w*16+16)
// snd/rcv read from global (64 consecutive ints/block, L1-broadcast-hot).
// 3 barriers. LDS exactly 32 KiB; launch_bounds(256,4) keeps VGPR~60 (no spill)
// while HW occupancy can reach 5 blocks/CU.
// ---------------------------------------------------------------------------
__global__ __launch_bounds__(256, 4)
void msg_kernel(const float* __restrict__ h, const float* __restrict__ efeat,
                const int* __restrict__ snd, const int* __restrict__ rcv,
                const bf16_t* __restrict__ Wp1, const float* __restrict__ b1,
                const bf16_t* __restrict__ Wp2, const float* __restrict__ b2,
                float* __restrict__ agg)
{
    __shared__ bf16_t s_buf[64 * 256];   // 32768 B exactly — nothing else in LDS

    const int t  = threadIdx.x;
    const int e0 = blockIdx.x * 64;

    // gather m_in = [e | h_s | h_r] : 64 rows x 192 cols (float4 granularity)
    #pragma unroll
    for (int it = 0; it < 12; ++it) {
        int i   = t + it * 256;        // < 3072 = 64*48
        int ee  = i / 48;
        int c4  = i - ee * 48;
        int col = c4 * 4;
        const float* srcp;
        if (col < DF)          srcp = efeat + (size_t)(e0 + ee) * DF + col;
        else if (col < 2 * DF) srcp = h + (size_t)snd[e0 + ee] * DF + (col - DF);
        else                   srcp = h + (size_t)rcv[e0 + ee] * DF + (col - 2 * DF);
        float4 v = *reinterpret_cast<const float4*>(srcp);
        bf16x4 bv;
        bv[0] = (bf16_t)v.x; bv[1] = (bf16_t)v.y; bv[2] = (bf16_t)v.z; bv[3] = (bf16_t)v.w;
        *reinterpret_cast<bf16x4*>(&s_buf[swz(ee, col)]) = bv;
    }
    __syncthreads();

    const int w = t >> 6;
    const int l = t & 63;
    const int q = l >> 4;
    const int r = l & 15;

    // ---- layer 1: M=64 (4 row-frags), N=64 per wave (4 ct) ----
    f32x4 acc[4][4];   // [g][am]
    #pragma unroll
    for (int g = 0; g < 4; ++g)
        #pragma unroll
        for (int am = 0; am < 4; ++am) acc[g][am] = (f32x4){0.f, 0.f, 0.f, 0.f};

    #pragma unroll
    for (int kb = 0; kb < 6; ++kb) {
        bf16x8 a[4];
        #pragma unroll
        for (int am = 0; am < 4; ++am)
            a[am] = *reinterpret_cast<const bf16x8*>(&s_buf[swz(am * 16 + r, kb * 32 + q * 8)]);
        #pragma unroll
        for (int g = 0; g < 4; ++g) {
            int ct = w * 4 + g;
            bf16x8 b = *reinterpret_cast<const bf16x8*>(Wp1 + ((size_t)(kb * 16 + ct) * 64 + l) * 8);
            #pragma unroll
            for (int am = 0; am < 4; ++am)
                acc[g][am] = __builtin_amdgcn_mfma_f32_16x16x32_bf16(a[am], b, acc[g][am], 0, 0, 0);
        }
    }
    __syncthreads();   // everyone done reading the input tile

    // bias + relu -> c1 into s_buf (row = edge, col = hidden unit)
    #pragma unroll
    for (int g = 0; g < 4; ++g) {
        int col = (w * 4 + g) * 16 + r;
        float bias = b1[col];
        #pragma unroll
        for (int am = 0; am < 4; ++am)
            #pragma unroll
            for (int j = 0; j < 4; ++j)
                s_buf[swz(am * 16 + q * 4 + j, col)] =
                    (bf16_t)fmaxf(acc[g][am][j] + bias, 0.f);
    }
    __syncthreads();   // c1 complete

    // ---- layer 2: M=64, N=16 per wave (ct = w) ----
    f32x4 acc2[4];
    #pragma unroll
    for (int am = 0; am < 4; ++am) acc2[am] = (f32x4){0.f, 0.f, 0.f, 0.f};

    #pragma unroll
    for (int kb = 0; kb < 8; ++kb) {
        bf16x8 a[4];
        #pragma unroll
        for (int am = 0; am < 4; ++am)
            a[am] = *reinterpret_cast<const bf16x8*>(&s_buf[swz(am * 16 + r, kb * 32 + q * 8)]);
        bf16x8 b = *reinterpret_cast<const bf16x8*>(Wp2 + ((size_t)(kb * 4 + w) * 64 + l) * 8);
        #pragma unroll
        for (int am = 0; am < 4; ++am)
            acc2[am] = __builtin_amdgcn_mfma_f32_16x16x32_bf16(a[am], b, acc2[am], 0, 0, 0);
    }

    // scatter (+bias): col = w*16 + r. rcv re-read from global (L1-hot, broadcast).
    float bias2 = b2[w * 16 + r];
    #pragma unroll
    for (int am = 0; am < 4; ++am)
        #pragma unroll
        for (int j = 0; j < 4; ++j) {
            int el = am * 16 + q * 4 + j;
            int rv = rcv[e0 + el];
            atomicAdd(agg + (size_t)rv * DF + w * 16 + r, acc2[am][j] + bias2);
        }
}

// ---------------------------------------------------------------------------
// Node-update kernel: 64 nodes/block, same template, K=128, residual store.
// Alias-safe when agg==out: agg reads happen only in the gather (pre-barrier);
// stores come after the final barrier.
// ---------------------------------------------------------------------------
__global__ __launch_bounds__(256, 4)
void upd_kernel(const float* __restrict__ h, const float* __restrict__ agg,
                const bf16_t* __restrict__ Wp1, const float* __restrict__ b1,
                const bf16_t* __restrict__ Wp2, const float* __restrict__ b2,
                float* __restrict__ out)
{
    __shared__ bf16_t s_buf[64 * 256];   // 32768 B exactly

    const int t  = threadIdx.x;
    const int n0 = blockIdx.x * 64;

    // gather u_in = [h | agg] : 64 rows x 128 cols
    #pragma unroll
    for (int it = 0; it < 8; ++it) {
        int i    = t + it * 256;       // < 2048 = 64*32
        int nn   = i >> 5;
        int col  = (i & 31) * 4;
        int node = n0 + nn;
        float4 v;
        if (node < NNODES) {
            const float* srcp = (col < DF) ? (h + (size_t)node * DF + col)
                                           : (agg + (size_t)node * DF + (col - DF));
            v = *reinterpret_cast<const float4*>(srcp);
        } else {
            v.x = 0.f; v.y = 0.f; v.z = 0.f; v.w = 0.f;
        }
        bf16x4 bv;
        bv[0] = (bf16_t)v.x; bv[1] = (bf16_t)v.y; bv[2] = (bf16_t)v.z; bv[3] = (bf16_t)v.w;
        *reinterpret_cast<bf16x4*>(&s_buf[swz(nn, col)]) = bv;
    }
    __syncthreads();

    const int w = t >> 6;
    const int l = t & 63;
    const int q = l >> 4;
    const int r = l & 15;

    f32x4 acc[4][4];
    #pragma unroll
    for (int g = 0; g < 4; ++g)
        #pragma unroll
        for (int am = 0; am < 4; ++am) acc[g][am] = (f32x4){0.f, 0.f, 0.f, 0.f};

    #pragma unroll
    for (int kb = 0; kb < 4; ++kb) {
        bf16x8 a[4];
        #pragma unroll
        for (int am = 0; am < 4; ++am)
            a[am] = *reinterpret_cast<const bf16x8*>(&s_buf[swz(am * 16 + r, kb * 32 + q * 8)]);
        #pragma unroll
        for (int g = 0; g < 4; ++g) {
            int ct = w * 4 + g;
            bf16x8 b = *reinterpret_cast<const bf16x8*>(Wp1 + ((size_t)(kb * 16 + ct) * 64 + l) * 8);
            #pragma unroll
            for (int am = 0; am < 4; ++am)
                acc[g][am] = __builtin_amdgcn_mfma_f32_16x16x32_bf16(a[am], b, acc[g][am], 0, 0, 0);
        }
    }
    __syncthreads();

    #pragma unroll
    for (int g = 0; g < 4; ++g) {
        int col = (w * 4 + g) * 16 + r;
        float bias = b1[col];
        #pragma unroll
        for (int am = 0; am < 4; ++am)
            #pragma unroll
            for (int j = 0; j < 4; ++j)
                s_buf[swz(am * 16 + q * 4 + j, col)] =
                    (bf16_t)fmaxf(acc[g][am][j] + bias, 0.f);
    }
    __syncthreads();

    f32x4 acc2[4];
    #pragma unroll
    for (int am = 0; am < 4; ++am) acc2[am] = (f32x4){0.f, 0.f, 0.f, 0.f};

    #pragma unroll
    for (int kb = 0; kb < 8; ++kb) {
        bf16x8 a[4];
        #pragma unroll
        for (int am = 0; am < 4; ++am)
            a[am] = *reinterpret_cast<const bf16x8*>(&s_buf[swz(am * 16 + r, kb * 32 + q * 8)]);
        bf16x8 b = *reinterpret_cast<const bf16x8*>(Wp2 + ((size_t)(kb * 4 + w) * 64 + l) * 8);
        #pragma unroll
        for (int am = 0; am < 4; ++am)
            acc2[am] = __builtin_amdgcn_mfma_f32_16x16x32_bf16(a[am], b, acc2[am], 0, 0, 0);
    }

    // residual store: out = h + dh  (col = w*16 + r)
    float bias2 = b2[w * 16 + r];
    #pragma unroll
    for (int am = 0; am < 4; ++am)
        #pragma unroll
        for (int j = 0; j < 4; ++j) {
            int node = n0 + am * 16 + q * 4 + j;
            if (node < NNODES) {
                int col = w * 16 + r;
                out[(size_t)node * DF + col] =
                    h[(size_t)node * DF + col] + acc2[am][j] + bias2;
            }
        }
}

extern "C" void kernel_launch(void* const* d_in, const int* in_sizes, int n_in,
                              void* d_out, int out_size, void* d_ws, size_t ws_size,
                              hipStream_t stream)
{
    const float* h    = (const float*)d_in[0];
    const float* e    = (const float*)d_in[1];
    const int*   snd  = (const int*)d_in[2];
    const int*   rcv  = (const int*)d_in[3];
    const float* W_m1 = (const float*)d_in[4];
    const float* b_m1 = (const float*)d_in[5];
    const float* W_m2 = (const float*)d_in[6];
    const float* b_m2 = (const float*)d_in[7];
    const float* W_u1 = (const float*)d_in[8];
    const float* b_u1 = (const float*)d_in[9];
    const float* W_u2 = (const float*)d_in[10];
    const float* b_u2 = (const float*)d_in[11];
    float* out = (float*)d_out;

    const size_t agg_bytes = (size_t)NNODES * DF * sizeof(float);   // 12.8 MB
    const size_t wp_bytes  = 114688 * sizeof(bf16_t);               // 229 KB

    float*  agg;
    bf16_t* wp;
    if (ws_size >= agg_bytes + wp_bytes) {
        agg = (float*)d_ws;
        wp  = (bf16_t*)((char*)d_ws + agg_bytes);
    } else {
        agg = out;               // alias-safe per upd_kernel structure
        wp  = (bf16_t*)d_ws;
    }

    bf16_t* Wp_m1 = wp;
    bf16_t* Wp_m2 = wp + 49152;
    bf16_t* Wp_u1 = wp + 65536;
    bf16_t* Wp_u2 = wp + 98304;

    prep_kernel<<<448, 256, 0, stream>>>(W_m1, W_m2, W_u1, W_u2, wp);
    hipMemsetAsync(agg, 0, agg_bytes, stream);

    msg_kernel<<<NEDGES / 64, 256, 0, stream>>>(h, e, snd, rcv,
                                                Wp_m1, b_m1, Wp_m2, b_m2, agg);
    upd_kernel<<<(NNODES + 63) / 64, 256, 0, stream>>>(h, agg,
                                                       Wp_u1, b_u1, Wp_u2, b_u2, out);
}

// Round 6
// 231.336 us; speedup vs baseline: 2.6087x; 1.8161x over previous
//
#include <hip/hip_runtime.h>
#include <hip/hip_bf16.h>
#include <cstdint>
#include <cstddef>

#define NNODES 50000
#define NEDGES 800000
#define DF 64
#define KM 192      // msg MLP input dim (3*D)
#define KU 128      // upd MLP input dim (2*D)
#define SROW 264    // LDS row stride in bf16 elems (528 B, 16B-aligned; proven ~free in r3)

typedef __bf16 bf16_t;
typedef __bf16 bf16x8 __attribute__((ext_vector_type(8)));
typedef __bf16 bf16x4 __attribute__((ext_vector_type(4)));
typedef float  f32x4  __attribute__((ext_vector_type(4)));

// ---------------------------------------------------------------------------
// Weight packing: W[K][N] fp32 row-major -> bf16 MFMA B-fragments.
// Fragment (kblk, ct): lane l, elem j holds W[kblk*32 + (l>>4)*8 + j][ct*16 + (l&15)]
// Flat: ((kblk*(N/16) + ct)*64 + l)*8 + j.
// Segments: Wm1 @0 (49152), Wm2 @49152 (16384), Wu1 @65536 (32768), Wu2 @98304 (16384).
// ---------------------------------------------------------------------------
__global__ void prep_kernel(const float* __restrict__ Wm1, const float* __restrict__ Wm2,
                            const float* __restrict__ Wu1, const float* __restrict__ Wu2,
                            bf16_t* __restrict__ wp)
{
    int idx = blockIdx.x * 256 + threadIdx.x;
    const float* src; int N; int off; int local;
    if (idx < 49152)       { src = Wm1; N = 256; off = 0;     local = idx; }
    else if (idx < 65536)  { src = Wm2; N = 64;  off = 49152; local = idx - 49152; }
    else if (idx < 98304)  { src = Wu1; N = 256; off = 65536; local = idx - 65536; }
    else if (idx < 114688) { src = Wu2; N = 64;  off = 98304; local = idx - 98304; }
    else return;
    int j    = local & 7;
    int l    = (local >> 3) & 63;
    int frag = local >> 9;
    int nct  = N >> 4;
    int kblk = frag / nct;
    int ct   = frag - kblk * nct;
    int k = kblk * 32 + (l >> 4) * 8 + j;
    int n = ct * 16 + (l & 15);
    wp[off + local] = (bf16_t)src[(size_t)k * N + n];
}

__device__ __forceinline__ void st_bf16x4(bf16_t* p, float4 v) {
    bf16x4 bv;
    bv[0] = (bf16_t)v.x; bv[1] = (bf16_t)v.y; bv[2] = (bf16_t)v.z; bv[3] = (bf16_t)v.w;
    *reinterpret_cast<bf16x4*>(p) = bv;
}

// ---------------------------------------------------------------------------
// Message kernel: 128 edges/block, 512 threads (8 waves).
// Layer1: wave w computes ALL 128 edges (8 A-frags) x cols [(w*2)*16,(w*2+2)*16)
//   -> each B-fragment feeds 8 MFMAs; block reads Wm1 exactly once per 128
//   edges (2x less per-edge B traffic than r3).
// Layer2: wave w: edge half m2=w>>2 (64 rows), col tile ct2=w&3 (16 cols).
// Branchless segmented gather (no int div, no 3-way divergence).
// LDS 128*528 + 1KB idx = 68.6 KB -> 2 blocks/CU (16 waves, same occupancy
// regime as r3). launch_bounds(512,4) => VGPR cap 128; acc needs ~95.
// ---------------------------------------------------------------------------
__global__ __launch_bounds__(512, 4)
void msg_kernel(const float* __restrict__ h, const float* __restrict__ efeat,
                const int* __restrict__ snd, const int* __restrict__ rcv,
                const bf16_t* __restrict__ Wp1, const float* __restrict__ b1,
                const bf16_t* __restrict__ Wp2, const float* __restrict__ b2,
                float* __restrict__ agg)
{
    __shared__ bf16_t s_buf[128 * SROW];   // 67584 B
    __shared__ int s_snd[128];
    __shared__ int s_rcv[128];

    const int t  = threadIdx.x;
    const int e0 = blockIdx.x * 128;

    if (t < 128)      s_snd[t]       = snd[e0 + t];
    else if (t < 256) s_rcv[t - 128] = rcv[e0 + t - 128];
    __syncthreads();

    // gather m_in = [e | h_s | h_r], 3 branchless segments.
    // each segment: 128 rows x 16 float4 = 2048 loads, 4 iters of 512 threads.
    #pragma unroll
    for (int it = 0; it < 4; ++it) {
        int i = t + it * 512; int row = i >> 4; int col = (i & 15) * 4;
        float4 v = *reinterpret_cast<const float4*>(efeat + (size_t)(e0 + row) * DF + col);
        st_bf16x4(&s_buf[row * SROW + col], v);
    }
    #pragma unroll
    for (int it = 0; it < 4; ++it) {
        int i = t + it * 512; int row = i >> 4; int col = (i & 15) * 4;
        float4 v = *reinterpret_cast<const float4*>(h + (size_t)s_snd[row] * DF + col);
        st_bf16x4(&s_buf[row * SROW + DF + col], v);
    }
    #pragma unroll
    for (int it = 0; it < 4; ++it) {
        int i = t + it * 512; int row = i >> 4; int col = (i & 15) * 4;
        float4 v = *reinterpret_cast<const float4*>(h + (size_t)s_rcv[row] * DF + col);
        st_bf16x4(&s_buf[row * SROW + 2 * DF + col], v);
    }
    __syncthreads();

    const int w = t >> 6;      // wave 0..7
    const int l = t & 63;
    const int q = l >> 4;
    const int r = l & 15;

    // ---- layer 1: M=128 (8 A-frags), N=32 per wave (ct = w*2, w*2+1) ----
    f32x4 acc[2][8];
    #pragma unroll
    for (int g = 0; g < 2; ++g)
        #pragma unroll
        for (int am = 0; am < 8; ++am) acc[g][am] = (f32x4){0.f, 0.f, 0.f, 0.f};

    #pragma unroll
    for (int kb = 0; kb < 6; ++kb) {
        bf16x8 b0 = *reinterpret_cast<const bf16x8*>(Wp1 + ((size_t)(kb * 16 + w * 2 + 0) * 64 + l) * 8);
        bf16x8 b1f = *reinterpret_cast<const bf16x8*>(Wp1 + ((size_t)(kb * 16 + w * 2 + 1) * 64 + l) * 8);
        #pragma unroll
        for (int am = 0; am < 8; ++am) {
            bf16x8 a = *reinterpret_cast<const bf16x8*>(&s_buf[(am * 16 + r) * SROW + kb * 32 + q * 8]);
            acc[0][am] = __builtin_amdgcn_mfma_f32_16x16x32_bf16(a, b0,  acc[0][am], 0, 0, 0);
            acc[1][am] = __builtin_amdgcn_mfma_f32_16x16x32_bf16(a, b1f, acc[1][am], 0, 0, 0);
        }
    }
    __syncthreads();   // all waves done reading the input tile

    // bias + relu -> c1 into s_buf (row = edge, col = hidden unit)
    #pragma unroll
    for (int g = 0; g < 2; ++g) {
        int col = (w * 2 + g) * 16 + r;
        float bias = b1[col];
        #pragma unroll
        for (int am = 0; am < 8; ++am)
            #pragma unroll
            for (int j = 0; j < 4; ++j)
                s_buf[(am * 16 + q * 4 + j) * SROW + col] =
                    (bf16_t)fmaxf(acc[g][am][j] + bias, 0.f);
    }
    __syncthreads();   // c1 complete

    // ---- layer 2: wave w -> rows [m2*64, m2*64+64), cols [ct2*16, ct2*16+16) ----
    const int m2  = w >> 2;
    const int ct2 = w & 3;
    f32x4 acc2[4];
    #pragma unroll
    for (int am = 0; am < 4; ++am) acc2[am] = (f32x4){0.f, 0.f, 0.f, 0.f};

    #pragma unroll
    for (int kb = 0; kb < 8; ++kb) {
        bf16x8 b = *reinterpret_cast<const bf16x8*>(Wp2 + ((size_t)(kb * 4 + ct2) * 64 + l) * 8);
        #pragma unroll
        for (int am = 0; am < 4; ++am) {
            bf16x8 a = *reinterpret_cast<const bf16x8*>(&s_buf[(m2 * 64 + am * 16 + r) * SROW + kb * 32 + q * 8]);
            acc2[am] = __builtin_amdgcn_mfma_f32_16x16x32_bf16(a, b, acc2[am], 0, 0, 0);
        }
    }

    // scatter (+bias): 16 fp32 atomics/thread, 64B-contiguous per 16-lane group
    float bias2 = b2[ct2 * 16 + r];
    #pragma unroll
    for (int am = 0; am < 4; ++am)
        #pragma unroll
        for (int j = 0; j < 4; ++j) {
            int erow = m2 * 64 + am * 16 + q * 4 + j;
            atomicAdd(agg + (size_t)s_rcv[erow] * DF + ct2 * 16 + r, acc2[am][j] + bias2);
        }
}

// ---------------------------------------------------------------------------
// Node-update kernel: r3's proven version (64 nodes/block, 4 waves, N-split).
// Alias-safe when agg==out: agg reads happen only in the gather (pre-barrier);
// stores come after the final barrier.
// ---------------------------------------------------------------------------
__global__ __launch_bounds__(256, 4)
void upd_kernel(const float* __restrict__ h, const float* __restrict__ agg,
                const bf16_t* __restrict__ Wp1, const float* __restrict__ b1,
                const bf16_t* __restrict__ Wp2, const float* __restrict__ b2,
                float* __restrict__ out)
{
    __shared__ bf16_t s_buf[64 * SROW];

    const int t  = threadIdx.x;
    const int n0 = blockIdx.x * 64;

    // gather u_in = [h | agg] : 64 rows x 128 cols
    #pragma unroll
    for (int it = 0; it < 8; ++it) {
        int i    = t + it * 256;       // < 2048 = 64*32
        int nn   = i >> 5;
        int col  = (i & 31) * 4;
        int node = n0 + nn;
        float4 v;
        if (node < NNODES) {
            const float* srcp = (col < DF) ? (h + (size_t)node * DF + col)
                                           : (agg + (size_t)node * DF + (col - DF));
            v = *reinterpret_cast<const float4*>(srcp);
        } else {
            v.x = 0.f; v.y = 0.f; v.z = 0.f; v.w = 0.f;
        }
        st_bf16x4(&s_buf[nn * SROW + col], v);
    }
    __syncthreads();

    const int w = t >> 6;
    const int l = t & 63;
    const int q = l >> 4;
    const int r = l & 15;

    f32x4 acc[4][4];
    #pragma unroll
    for (int g = 0; g < 4; ++g)
        #pragma unroll
        for (int am = 0; am < 4; ++am) acc[g][am] = (f32x4){0.f, 0.f, 0.f, 0.f};

    #pragma unroll
    for (int kb = 0; kb < 4; ++kb) {
        bf16x8 a[4];
        #pragma unroll
        for (int am = 0; am < 4; ++am)
            a[am] = *reinterpret_cast<const bf16x8*>(&s_buf[(am * 16 + r) * SROW + kb * 32 + q * 8]);
        #pragma unroll
        for (int g = 0; g < 4; ++g) {
            int ct = w * 4 + g;
            bf16x8 b = *reinterpret_cast<const bf16x8*>(Wp1 + ((size_t)(kb * 16 + ct) * 64 + l) * 8);
            #pragma unroll
            for (int am = 0; am < 4; ++am)
                acc[g][am] = __builtin_amdgcn_mfma_f32_16x16x32_bf16(a[am], b, acc[g][am], 0, 0, 0);
        }
    }
    __syncthreads();

    #pragma unroll
    for (int g = 0; g < 4; ++g) {
        int col = (w * 4 + g) * 16 + r;
        float bias = b1[col];
        #pragma unroll
        for (int am = 0; am < 4; ++am)
            #pragma unroll
            for (int j = 0; j < 4; ++j)
                s_buf[(am * 16 + q * 4 + j) * SROW + col] =
                    (bf16_t)fmaxf(acc[g][am][j] + bias, 0.f);
    }
    __syncthreads();

    f32x4 acc2[4];
    #pragma unroll
    for (int am = 0; am < 4; ++am) acc2[am] = (f32x4){0.f, 0.f, 0.f, 0.f};

    #pragma unroll
    for (int kb = 0; kb < 8; ++kb) {
        bf16x8 a[4];
        #pragma unroll
        for (int am = 0; am < 4; ++am)
            a[am] = *reinterpret_cast<const bf16x8*>(&s_buf[(am * 16 + r) * SROW + kb * 32 + q * 8]);
        bf16x8 b = *reinterpret_cast<const bf16x8*>(Wp2 + ((size_t)(kb * 4 + w) * 64 + l) * 8);
        #pragma unroll
        for (int am = 0; am < 4; ++am)
            acc2[am] = __builtin_amdgcn_mfma_f32_16x16x32_bf16(a[am], b, acc2[am], 0, 0, 0);
    }

    // residual store: out = h + dh  (col = w*16 + r)
    float bias2 = b2[w * 16 + r];
    #pragma unroll
    for (int am = 0; am < 4; ++am)
        #pragma unroll
        for (int j = 0; j < 4; ++j) {
            int node = n0 + am * 16 + q * 4 + j;
            if (node < NNODES) {
                int col = w * 16 + r;
                out[(size_t)node * DF + col] =
                    h[(size_t)node * DF + col] + acc2[am][j] + bias2;
            }
        }
}

extern "C" void kernel_launch(void* const* d_in, const int* in_sizes, int n_in,
                              void* d_out, int out_size, void* d_ws, size_t ws_size,
                              hipStream_t stream)
{
    const float* h    = (const float*)d_in[0];
    const float* e    = (const float*)d_in[1];
    const int*   snd  = (const int*)d_in[2];
    const int*   rcv  = (const int*)d_in[3];
    const float* W_m1 = (const float*)d_in[4];
    const float* b_m1 = (const float*)d_in[5];
    const float* W_m2 = (const float*)d_in[6];
    const float* b_m2 = (const float*)d_in[7];
    const float* W_u1 = (const float*)d_in[8];
    const float* b_u1 = (const float*)d_in[9];
    const float* W_u2 = (const float*)d_in[10];
    const float* b_u2 = (const float*)d_in[11];
    float* out = (float*)d_out;

    const size_t agg_bytes = (size_t)NNODES * DF * sizeof(float);   // 12.8 MB
    const size_t wp_bytes  = 114688 * sizeof(bf16_t);               // 229 KB

    float*  agg;
    bf16_t* wp;
    if (ws_size >= agg_bytes + wp_bytes) {
        agg = (float*)d_ws;
        wp  = (bf16_t*)((char*)d_ws + agg_bytes);
    } else {
        agg = out;               // alias-safe per upd_kernel structure
        wp  = (bf16_t*)d_ws;
    }

    bf16_t* Wp_m1 = wp;
    bf16_t* Wp_m2 = wp + 49152;
    bf16_t* Wp_u1 = wp + 65536;
    bf16_t* Wp_u2 = wp + 98304;

    prep_kernel<<<448, 256, 0, stream>>>(W_m1, W_m2, W_u1, W_u2, wp);
    hipMemsetAsync(agg, 0, agg_bytes, stream);

    msg_kernel<<<NEDGES / 128, 512, 0, stream>>>(h, e, snd, rcv,
                                                 Wp_m1, b_m1, Wp_m2, b_m2, agg);
    upd_kernel<<<(NNODES + 63) / 64, 256, 0, stream>>>(h, agg,
                                                       Wp_u1, b_u1, Wp_u2, b_u2, out);
}